// Round 6
// baseline (233.994 us; speedup 1.0000x reference)
//
#include <hip/hip_runtime.h>

#define HW    512
#define OUTW  128
#define NIMG  96                          // 32*3
#define N_HR  ((long long)NIMG*HW*HW)     // 25165824
#define N_LR  ((long long)NIMG*OUTW*OUTW) // 1572864
#define NBLK  (NIMG*8)                    // 768 blocks: (img, 16 out rows)

// PyTorch bicubic kernel, a = -0.75
__device__ __forceinline__ float cubic075(float x){
    float ax = fabsf(x);
    float ax2 = ax*ax, ax3 = ax2*ax;
    const float A = -0.75f;
    float f1 = (A+2.f)*ax3 - (A+3.f)*ax2 + 1.f;
    float f2 = A*ax3 - 5.f*A*ax2 + 8.f*A*ax - 4.f*A;
    return ax <= 1.f ? f1 : (ax < 2.f ? f2 : 0.f);
}

// scale=4 antialiased window: 16 taps, dist=(k-7.5)/4, normalized.
// Shift-invariant across all output positions (absmax=0.0 in R1-R5).
__device__ __forceinline__ void get_weights(float w[16]){
    float s = 0.f;
#pragma unroll
    for (int k = 0; k < 16; ++k){
        float d = ((float)k - 7.5f) * 0.25f;
        w[k] = cubic075(d);
        s += w[k];
    }
#pragma unroll
    for (int k = 0; k < 16; ++k) w[k] /= s;
}

// Fused single kernel. Block = (img, 16 output rows) = input rows s..s+75.
// Phase 1 (barrier-free, 19 iters x 4 rows): thread (rg=tid>>7, o=tid&127)
// h-filters out col o of row 4i+rg via 5 DIRECTLY-LOADED overlapping float4s
// (lane-contiguous -> 5 coalesced 1KB loads; overlap absorbed by L1).
// Border clamp = clamped quad bases + edge cndmasks (no shuffles, no LDS
// staging, no per-iter barrier). quad2 == cols 4o..4o+3 -> pix term fuses
// with one coalesced tgt load. H-results -> 38KB LDS tile.
// Phase 2 (after ONE barrier): vertical 16-tap from LDS (2-way bank = free),
// lr term. Reduction once at the very end.
__global__ __launch_bounds__(512, 6) void kmain(const float* __restrict__ pred,
                                                const float* __restrict__ tgt,
                                                const float* __restrict__ lr,
                                                double* __restrict__ part1,
                                                double* __restrict__ part2){
    const int b   = blockIdx.x;
    const int W   = ((b & 7) * (NBLK/8)) + (b >> 3);  // XCD owns 12 contiguous imgs
    const int img = W >> 3;
    const int grp = W & 7;
    const int o0  = grp << 4;                 // first output row
    const int s   = (o0 << 2) - 6;            // first (unclamped) input row
    const int tid = threadIdx.x;
    const int rg  = tid >> 7;                 // row-group 0..3
    const int o   = tid & 127;                // output column

    __shared__ float  hbuf[76][128];          // 38 KB h-filtered tile
    __shared__ double sred[16];

    float wt[16]; get_weights(wt);
    const float* P = pred + (size_t)img * (HW*HW);
    const float* T = tgt  + (size_t)img * (HW*HW);
    const float* L = lr   + (size_t)img * (OUTW*OUTW);

    // per-thread constant quad base columns, clamped to [0,508]
    int bq[5];
#pragma unroll
    for (int k = 0; k < 5; ++k)
        bq[k] = min(508, max(0, 4*o - 8 + 4*k));
    const int ctr = 4*o;                      // quad2 always == cols 4o..4o+3

    float pix_acc = 0.f, lr_acc = 0.f;

    for (int i = 0; i < 19; ++i){
        const int j   = 4*i + rg;             // local row 0..75 (wave-uniform)
        const int hin = min(HW-1, max(0, s + j));
        const float* R  = P + (size_t)hin * HW;
        const float* TR = T + (size_t)hin * HW;

        float4 q0 = *(const float4*)(R + bq[0]);
        float4 q1 = *(const float4*)(R + bq[1]);
        float4 q2 = *(const float4*)(R + bq[2]);
        float4 q3 = *(const float4*)(R + bq[3]);
        float4 q4 = *(const float4*)(R + bq[4]);
        float4 tq = *(const float4*)(TR + ctr);

        // 16 taps: arr[j+2] with arr[m]=quad[m>>2][m&3]; edge-clamped via
        // cndmask to q0.x (col 0) / q4.w (col 511). Verified o=0,1,2,125,126,127.
        float t0=q0.z, t1=q0.w, t2=q1.x, t3=q1.y, t4=q1.z, t5=q1.w,
              t6=q2.x, t7=q2.y, t8=q2.z, t9=q2.w, t10=q3.x, t11=q3.y,
              t12=q3.z, t13=q3.w, t14=q4.x, t15=q4.y;
        const int c0 = 4*o - 6;
        t0  = (c0 +  0 <   0) ? q0.x : t0;
        t1  = (c0 +  1 <   0) ? q0.x : t1;
        t2  = (c0 +  2 <   0) ? q0.x : t2;
        t3  = (c0 +  3 <   0) ? q0.x : t3;
        t4  = (c0 +  4 <   0) ? q0.x : t4;
        t5  = (c0 +  5 <   0) ? q0.x : t5;
        t10 = (c0 + 10 > 511) ? q4.w : t10;
        t11 = (c0 + 11 > 511) ? q4.w : t11;
        t12 = (c0 + 12 > 511) ? q4.w : t12;
        t13 = (c0 + 13 > 511) ? q4.w : t13;
        t14 = (c0 + 14 > 511) ? q4.w : t14;
        t15 = (c0 + 15 > 511) ? q4.w : t15;

        float h = wt[0]*t0 + wt[1]*t1 + wt[2]*t2 + wt[3]*t3
                + wt[4]*t4 + wt[5]*t5 + wt[6]*t6 + wt[7]*t7
                + wt[8]*t8 + wt[9]*t9 + wt[10]*t10 + wt[11]*t11
                + wt[12]*t12 + wt[13]*t13 + wt[14]*t14 + wt[15]*t15;
        hbuf[j][o] = h;

        // pix term over owned rows s+6..s+69 (j in [6,70)), wave-uniform cond
        if (j >= 6 && j < 70){
            pix_acc += fabsf(q2.x-tq.x) + fabsf(q2.y-tq.y)
                     + fabsf(q2.z-tq.z) + fabsf(q2.w-tq.w);
        }
    }

    __syncthreads();   // the only barrier: h-tile complete

    // Phase 2: vertical 16-tap. thread -> out rows rg, rg+4, rg+8, rg+12 at col o.
#pragma unroll
    for (int m = 0; m < 4; ++m){
        const int q = rg + 4*m;               // local out row 0..15
        float acc = 0.f;
#pragma unroll
        for (int r = 0; r < 16; ++r)
            acc += wt[r] * hbuf[4*q + r][o];
        lr_acc += fabsf(acc - L[(size_t)(o0 + q) * OUTW + o]);
    }

    // reduction: per-wave shuffle, then 8 wave-partials via LDS
    const int l = tid & 63, wv = tid >> 6;
#pragma unroll
    for (int off = 32; off > 0; off >>= 1){
        pix_acc += __shfl_down(pix_acc, off, 64);
        lr_acc  += __shfl_down(lr_acc,  off, 64);
    }
    if (l == 0){ sred[wv] = (double)pix_acc; sred[8+wv] = (double)lr_acc; }
    __syncthreads();
    if (tid == 0){
        double S1 = 0.0;
#pragma unroll
        for (int k = 0; k < 8; ++k) S1 += sred[k];
        part1[b] = S1;
    }
    if (tid == 64){
        double S2 = 0.0;
#pragma unroll
        for (int k = 0; k < 8; ++k) S2 += sred[8+k];
        part2[b] = S2;
    }
}

__global__ __launch_bounds__(256) void k3(const double* __restrict__ part1,
                                          const double* __restrict__ part2,
                                          float* __restrict__ out){
    const int t = threadIdx.x;
    double v1 = 0.0, v2 = 0.0;
    for (int i = t; i < NBLK; i += 256){
        v1 += part1[i];
        v2 += part2[i];
    }
#pragma unroll
    for (int off = 32; off > 0; off >>= 1){
        v1 += __shfl_down(v1, off, 64);
        v2 += __shfl_down(v2, off, 64);
    }
    __shared__ double s1[4], s2[4];
    const int lane = t & 63, wid = t >> 6;
    if (lane == 0){ s1[wid] = v1; s2[wid] = v2; }
    __syncthreads();
    if (t == 0){
        double S1 = s1[0]+s1[1]+s1[2]+s1[3];
        double S2 = s2[0]+s2[1]+s2[2]+s2[3];
        float pix     = (float)(S1 / (double)N_HR);
        float lr_term = (float)(S2 / (double)N_LR);
        float pair    = 0.f;
        float consist = 1.0f * lr_term + 1.0f * pair;   // LAM_LR, LAM_PAIR
        float total   = pix + 0.1f * consist;           // LAM_CONSIST
        out[0] = total; out[1] = pix; out[2] = consist; out[3] = lr_term; out[4] = pair;
    }
}

extern "C" void kernel_launch(void* const* d_in, const int* in_sizes, int n_in,
                              void* d_out, int out_size, void* d_ws, size_t ws_size,
                              hipStream_t stream){
    const float* pred = (const float*)d_in[0];
    const float* tgt  = (const float*)d_in[1];
    const float* lrr  = (const float*)d_in[2];
    float* out = (float*)d_out;

    double* part1 = (double*)d_ws;        // 768 doubles, all written
    double* part2 = part1 + NBLK;         // 768 doubles, all written

    kmain<<<NBLK, 512, 0, stream>>>(pred, tgt, lrr, part1, part2);
    k3<<<1, 256, 0, stream>>>(part1, part2, out);
}